// Round 1
// baseline (51.637 us; speedup 1.0000x reference)
//
#include <hip/hip_runtime.h>
#include <hip/hip_bf16.h>

#define B_DIM 128
#define C_DIM 128
#define T_DIM 777
#define T_PAD 832   // 26 * 32
#define P_DIM 500
#define P_PAD 512
#define NCLS  5
#define EPSV  1e-4f

typedef unsigned short u16;
typedef __attribute__((ext_vector_type(8))) short short8;   // 8 bf16 = 4 VGPR (guide §3)
typedef __attribute__((ext_vector_type(4))) float f32x4;

__device__ __forceinline__ u16 f2bf(float f) {
    unsigned u = __float_as_uint(f);
    u += 0x7FFFu + ((u >> 16) & 1u);     // RNE
    return (u16)(u >> 16);
}

// ---------------- kernel 1: x fp32 -> xbf[B][T_PAD][C] bf16 + x2[B][T_PAD] ----------------
__global__ __launch_bounds__(256) void prep_x(const float* __restrict__ x,
                                              u16* __restrict__ xbf,
                                              float* __restrict__ x2) {
    const int tc = blockIdx.x;           // 0..12 (64 t's each)
    const int b  = blockIdx.y;
    const int tid = threadIdx.x, w = tid >> 6, l = tid & 63;
    __shared__ __align__(16) u16 xt[64][136];  // +8 pad
    const int t_loc = w * 16 + (l & 15);
    const int cg = l >> 4;                     // 0..3
    const int t = tc * 64 + t_loc;
    const float* xb = x + (size_t)b * C_DIM * T_DIM;
    float acc = 0.f;
#pragma unroll 8
    for (int c0 = 0; c0 < C_DIM; c0 += 4) {
        int c = c0 + cg;
        float v = (t < T_DIM) ? xb[c * T_DIM + t] : 0.f;
        acc = fmaf(v, v, acc);
        xt[t_loc][c] = f2bf(v);
    }
    acc += __shfl_xor(acc, 16);
    acc += __shfl_xor(acc, 32);
    if (cg == 0) x2[b * T_PAD + t] = (t < T_DIM) ? acc : 1e30f;
    __syncthreads();
    int4* dst = (int4*)(xbf + ((size_t)b * T_PAD + tc * 64) * C_DIM);
#pragma unroll
    for (int q = 0; q < 4; ++q) {
        int f = q * 256 + tid;                 // 1024 16B-granules
        int tr = f >> 4, g = f & 15;
        dst[f] = *(const int4*)((const char*)xt + tr * 272 + g * 16);
    }
}

// ---------------- kernel 2: p2[p] = ||proto_p||^2 ----------------
__global__ void prep_p2(const float* __restrict__ proto, float* __restrict__ p2) {
    int p = blockIdx.x * 64 + threadIdx.x;     // 0..511
    float a = 0.f;
    if (p < P_DIM) {
        const float* pr = proto + p * C_DIM;
#pragma unroll 8
        for (int c = 0; c < C_DIM; ++c) { float v = pr[c]; a = fmaf(v, v, a); }
    }
    p2[p] = (p < P_DIM) ? a : 0.f;
}

// ---------------- kernel 3: fused MFMA GEMM + min-over-t + sim ----------------
__global__ __launch_bounds__(256, 2) void gemm_min(const u16* __restrict__ xbf,
                                                   const float* __restrict__ x2,
                                                   const float* __restrict__ proto,
                                                   const float* __restrict__ p2ws,
                                                   float* __restrict__ simws) {
    // XCD-bijective decode: XCD x owns b in [x*16, x*16+16), 4 p-tiles each
    const int o = blockIdx.x;                  // 0..511
    const int xcd = o & 7, j = o >> 3;
    const int b = xcd * 16 + (j >> 2);
    const int pt = j & 3;
    const int tid = threadIdx.x, w = tid >> 6, l = tid & 63;
    const int wp = pt * 128 + w * 32;          // wave's p base
    const int row16 = l & 15, kq = l >> 4;     // kq: 0..3

    __shared__ __align__(16) char smem[32 * 256];   // 32 t-rows x 128 c bf16, XOR-swizzled 16B granules

    // --- prologue: prototype A-frags (registers) + p2 ---
    short8 afr[2][4];
#pragma unroll
    for (int ps = 0; ps < 2; ++ps) {
        int r = wp + ps * 16 + row16;
#pragma unroll
        for (int kst = 0; kst < 4; ++kst) {
            int k0 = kst * 32 + kq * 8;
            float f[8];
            if (r < P_DIM) {
                float4 u0 = *(const float4*)(proto + r * C_DIM + k0);
                float4 u1 = *(const float4*)(proto + r * C_DIM + k0 + 4);
                f[0]=u0.x; f[1]=u0.y; f[2]=u0.z; f[3]=u0.w;
                f[4]=u1.x; f[5]=u1.y; f[6]=u1.z; f[7]=u1.w;
            } else {
#pragma unroll
                for (int q = 0; q < 8; ++q) f[q] = 0.f;
            }
            short8 s;
#pragma unroll
            for (int q = 0; q < 8; ++q) s[q] = (short)f2bf(f[q]);
            afr[ps][kst] = s;
        }
    }
    float p2r[2][4];
#pragma unroll
    for (int ps = 0; ps < 2; ++ps)
#pragma unroll
        for (int q = 0; q < 4; ++q) p2r[ps][q] = p2ws[wp + ps * 16 + kq * 4 + q];

    // --- staging coords (16B granules; 512 per 32x128 tile) ---
    const int4* xg = (const int4*)xbf;
    const size_t base_g = (size_t)b * T_PAD * 16;
    const int f0 = tid, f1 = tid + 256;
    const int tl0 = f0 >> 4, g0 = f0 & 15;
    const int tl1 = f1 >> 4, g1 = f1 & 15;
    char* wr0 = smem + tl0 * 256 + ((g0 ^ (tl0 & 7)) << 4);
    char* wr1 = smem + tl1 * 256 + ((g1 ^ (tl1 & 7)) << 4);
    int4 v0 = xg[base_g + (size_t)tl0 * 16 + g0];
    int4 v1 = xg[base_g + (size_t)tl1 * 16 + g1];

    float minv[2][4];
#pragma unroll
    for (int ps = 0; ps < 2; ++ps)
#pragma unroll
        for (int q = 0; q < 4; ++q) minv[ps][q] = 1e30f;

    const float* x2b = x2 + b * T_PAD;

    for (int it = 0; it < T_PAD / 32; ++it) {
        *(int4*)wr0 = v0;
        *(int4*)wr1 = v1;
        if (it + 1 < T_PAD / 32) {
            v0 = xg[base_g + (size_t)((it + 1) * 32 + tl0) * 16 + g0];
            v1 = xg[base_g + (size_t)((it + 1) * 32 + tl1) * 16 + g1];
        }
        __syncthreads();

        f32x4 acc[2][2];
#pragma unroll
        for (int ps = 0; ps < 2; ++ps)
#pragma unroll
            for (int ts = 0; ts < 2; ++ts) acc[ps][ts] = (f32x4){0.f, 0.f, 0.f, 0.f};

#pragma unroll
        for (int kst = 0; kst < 4; ++kst) {
            short8 bfr[2];
#pragma unroll
            for (int ts = 0; ts < 2; ++ts) {
                int tl = ts * 16 + row16;
                int gr = (kst * 4 + kq) ^ (tl & 7);
                bfr[ts] = *(const short8*)(smem + tl * 256 + (gr << 4));
            }
#pragma unroll
            for (int ps = 0; ps < 2; ++ps)
#pragma unroll
                for (int ts = 0; ts < 2; ++ts)
                    acc[ps][ts] = __builtin_amdgcn_mfma_f32_16x16x32_bf16(
                        afr[ps][kst], bfr[ts], acc[ps][ts], 0, 0, 0);
        }
        float x2v0 = x2b[it * 32 + row16];
        float x2v1 = x2b[it * 32 + 16 + row16];
#pragma unroll
        for (int ps = 0; ps < 2; ++ps)
#pragma unroll
            for (int q = 0; q < 4; ++q) {
                minv[ps][q] = fminf(minv[ps][q], fmaf(-2.f, acc[ps][0][q], x2v0));
                minv[ps][q] = fminf(minv[ps][q], fmaf(-2.f, acc[ps][1][q], x2v1));
            }
        __syncthreads();
    }

    // min across 16 cols (lanes sharing kq group)
#pragma unroll
    for (int m = 1; m <= 8; m <<= 1)
#pragma unroll
        for (int ps = 0; ps < 2; ++ps)
#pragma unroll
            for (int q = 0; q < 4; ++q)
                minv[ps][q] = fminf(minv[ps][q], __shfl_xor(minv[ps][q], m));

    if (row16 == 0) {
#pragma unroll
        for (int ps = 0; ps < 2; ++ps)
#pragma unroll
            for (int q = 0; q < 4; ++q) {
                int p = wp + ps * 16 + kq * 4 + q;
                if (p < P_DIM) {
                    float md = fmaxf(minv[ps][q] + p2r[ps][q], 0.f);
                    simws[b * P_PAD + p] = logf((md + 1.f) / (md + EPSV));
                }
            }
    }
}

// ---------------- kernel 4: logits = sim @ W ----------------
__global__ void logits_k(const float* __restrict__ simws, const float* __restrict__ lw,
                         float* __restrict__ out) {
    int b = blockIdx.x, l = threadIdx.x;
    float a[NCLS] = {0.f, 0.f, 0.f, 0.f, 0.f};
    for (int p = l; p < P_DIM; p += 64) {
        float s = simws[b * P_PAD + p];
#pragma unroll
        for (int n = 0; n < NCLS; ++n) a[n] = fmaf(s, lw[p * NCLS + n], a[n]);
    }
#pragma unroll
    for (int m = 1; m <= 32; m <<= 1)
#pragma unroll
        for (int n = 0; n < NCLS; ++n) a[n] += __shfl_xor(a[n], m);
    if (l == 0) {
#pragma unroll
        for (int n = 0; n < NCLS; ++n) out[b * NCLS + n] = a[n];
    }
}

// ---------------- fallback (no workspace): slow but correct ----------------
__global__ __launch_bounds__(256) void fallback_k(const float* __restrict__ x,
                                                  const float* __restrict__ proto,
                                                  const float* __restrict__ lw,
                                                  float* __restrict__ out) {
    __shared__ float x2s[T_DIM];
    __shared__ float sims[P_DIM];
    int b = blockIdx.x, tid = threadIdx.x;
    for (int t = tid; t < T_DIM; t += 256) {
        float a = 0.f;
        for (int c = 0; c < C_DIM; ++c) { float v = x[((size_t)b * C_DIM + c) * T_DIM + t]; a = fmaf(v, v, a); }
        x2s[t] = a;
    }
    __syncthreads();
    for (int p = tid; p < P_DIM; p += 256) {
        float p2 = 0.f;
        for (int c = 0; c < C_DIM; ++c) { float v = proto[p * C_DIM + c]; p2 = fmaf(v, v, p2); }
        float mind = 1e30f;
        for (int t = 0; t < T_DIM; ++t) {
            float xp = 0.f;
            for (int c = 0; c < C_DIM; ++c)
                xp = fmaf(x[((size_t)b * C_DIM + c) * T_DIM + t], proto[p * C_DIM + c], xp);
            float d = fmaxf(x2s[t] - 2.f * xp + p2, 0.f);
            mind = fminf(mind, d);
        }
        sims[p] = logf((mind + 1.f) / (mind + EPSV));
    }
    __syncthreads();
    if (tid < NCLS) {
        float a = 0.f;
        for (int p = 0; p < P_DIM; ++p) a = fmaf(sims[p], lw[p * NCLS + tid], a);
        out[b * NCLS + tid] = a;
    }
}

extern "C" void kernel_launch(void* const* d_in, const int* in_sizes, int n_in,
                              void* d_out, int out_size, void* d_ws, size_t ws_size,
                              hipStream_t stream) {
    const float* x     = (const float*)d_in[0];
    const float* proto = (const float*)d_in[1];
    const float* lw    = (const float*)d_in[2];
    float* out = (float*)d_out;

    const size_t xbf_bytes = (size_t)B_DIM * T_PAD * C_DIM * 2;  // 27,262,976
    const size_t x2_off  = xbf_bytes;
    const size_t p2_off  = x2_off + (size_t)B_DIM * T_PAD * 4;
    const size_t sim_off = p2_off + (size_t)P_PAD * 4;
    const size_t need    = sim_off + (size_t)B_DIM * P_PAD * 4;

    if (ws_size >= need) {
        u16*   xbf = (u16*)d_ws;
        float* x2  = (float*)((char*)d_ws + x2_off);
        float* p2  = (float*)((char*)d_ws + p2_off);
        float* sim = (float*)((char*)d_ws + sim_off);
        prep_x  <<<dim3(T_PAD / 64, B_DIM), 256, 0, stream>>>(x, xbf, x2);
        prep_p2 <<<dim3(P_PAD / 64),        64,  0, stream>>>(proto, p2);
        gemm_min<<<dim3(512),               256, 0, stream>>>(xbf, x2, proto, p2, sim);
        logits_k<<<dim3(B_DIM),             64,  0, stream>>>(sim, lw, out);
    } else {
        fallback_k<<<dim3(B_DIM), 256, 0, stream>>>(x, proto, lw, out);
    }
}

// Round 2
// 43.146 us; speedup vs baseline: 1.1968x; 1.1968x over previous
//
#include <hip/hip_runtime.h>
#include <hip/hip_bf16.h>

#define B_DIM 128
#define C_DIM 128
#define T_DIM 777
#define P_DIM 500
#define P_PAD 512
#define NCLS  5
#define EPSV  1e-4f
#define NT    25          // ceil(777/32); tile 25 (t>=800) skipped entirely

typedef unsigned short u16;
typedef unsigned int   u32;
typedef __attribute__((ext_vector_type(8))) short short8;   // 8 bf16 = 4 VGPR
typedef __attribute__((ext_vector_type(4))) float f32x4;
typedef float float4u __attribute__((ext_vector_type(4), aligned(4)));  // 4B-aligned (row stride 777 is odd)

__device__ __forceinline__ u16 f2bf(float f) {
    u32 u = __float_as_uint(f);
    u += 0x7FFFu + ((u >> 16) & 1u);     // RNE
    return (u16)(u >> 16);
}

// ---------------- fused: x fp32 -> bf16 LDS transpose -> MFMA -> min over t ----------------
// grid 512 = b(128) x pt(2) x th(2); block 256 (4 waves); wave owns 64 protos.
// writes wsmin[b][p][th] = min over its t-half of (x2[t] - 2*x.p)   (p2/clamp/log deferred)
__global__ __launch_bounds__(256, 2) void fused_gemm_min(
    const float* __restrict__ x,
    const float* __restrict__ proto,
    float* __restrict__ wsmin) {

    const int o = blockIdx.x;                 // XCD-bijective: XCD owns 16 consecutive b's
    const int xcd = o & 7, j = o >> 3;        // j: 0..63
    const int b   = xcd * 16 + (j >> 2);
    const int pt  = (j >> 1) & 1, th = j & 1;
    const int it0 = th ? 13 : 0;
    const int itN = th ? NT : 13;

    const int tid = threadIdx.x;
    const int w = tid >> 6, l = tid & 63;
    const int row16 = l & 15, kq = l >> 4;    // kq: 0..3
    const int wp = pt * 256 + w * 64;         // wave's proto base (64 rows)

    // loader coords: thread owns 4 c-rows x 4 t-cols
    const int c0  = (tid >> 3) << 2;          // 0..124
    const int tl0 = (tid & 7) << 2;           // 0..28

    __shared__ __align__(16) char  smem[32 * 256];   // 32 t-rows x 128 c bf16, 16B-granule XOR swizzle
    __shared__ __align__(16) float x2p[4][32];       // per-wave x2 partials

    const float* xb = x + (size_t)b * C_DIM * T_DIM;

    // ---- prologue: prototype A-frags in registers (bf16) ----
    short8 afr[4][4];
#pragma unroll
    for (int ps = 0; ps < 4; ++ps) {
        const int r = wp + ps * 16 + row16;
#pragma unroll
        for (int kst = 0; kst < 4; ++kst) {
            const int k0 = kst * 32 + kq * 8;
            float f[8];
            if (r < P_DIM) {
                float4 u0 = *(const float4*)(proto + r * C_DIM + k0);
                float4 u1 = *(const float4*)(proto + r * C_DIM + k0 + 4);
                f[0]=u0.x; f[1]=u0.y; f[2]=u0.z; f[3]=u0.w;
                f[4]=u1.x; f[5]=u1.y; f[6]=u1.z; f[7]=u1.w;
            } else {
#pragma unroll
                for (int q = 0; q < 8; ++q) f[q] = 0.f;
            }
            short8 s8;
#pragma unroll
            for (int q = 0; q < 8; ++q) s8[q] = (short)f2bf(f[q]);
            afr[ps][kst] = s8;
        }
    }

    float vb[4][4];   // [c-row r][t-col j], all indices compile-time (rule #20)
    auto loadv = [&](int it) {
        const int tb = it * 32 + tl0;
        if (tb + 3 < T_DIM) {
#pragma unroll
            for (int r = 0; r < 4; ++r) {
                float4u u = *(const float4u*)(xb + (c0 + r) * T_DIM + tb);
                vb[r][0]=u[0]; vb[r][1]=u[1]; vb[r][2]=u[2]; vb[r][3]=u[3];
            }
        } else {
#pragma unroll
            for (int r = 0; r < 4; ++r)
#pragma unroll
                for (int jj = 0; jj < 4; ++jj) {
                    const int t = tb + jj;
                    vb[r][jj] = (t < T_DIM) ? xb[(c0 + r) * T_DIM + t] : 0.f;
                }
        }
    };

    loadv(it0);

    f32x4 minv[4];
#pragma unroll
    for (int ps = 0; ps < 4; ++ps) minv[ps] = (f32x4){1e30f, 1e30f, 1e30f, 1e30f};

    for (int it = it0; it < itN; ++it) {
        const int t0 = it * 32;

        // squares for x2 (fp32, before conversion)
        float s[4];
#pragma unroll
        for (int jj = 0; jj < 4; ++jj)
            s[jj] = vb[0][jj]*vb[0][jj] + vb[1][jj]*vb[1][jj]
                  + vb[2][jj]*vb[2][jj] + vb[3][jj]*vb[3][jj];

        // convert + transposed swizzled LDS write (4 x ds_write_b64)
#pragma unroll
        for (int jj = 0; jj < 4; ++jj) {
            const u32 lo = (u32)f2bf(vb[0][jj]) | ((u32)f2bf(vb[1][jj]) << 16);
            const u32 hi = (u32)f2bf(vb[2][jj]) | ((u32)f2bf(vb[3][jj]) << 16);
            const int tl  = tl0 + jj;
            const int off = tl * 256 + (((c0 >> 3) ^ (tl & 7)) << 4) + ((c0 & 4) << 1);
            *(uint2*)(smem + off) = make_uint2(lo, hi);
        }

        // reduce squares over the wave's 8 c-groups (lane bits 3..5)
#pragma unroll
        for (int m = 8; m <= 32; m <<= 1)
#pragma unroll
            for (int jj = 0; jj < 4; ++jj) s[jj] += __shfl_xor(s[jj], m);
        if ((l >> 3) == 0) {                       // lanes 0..7: tl0 == l*4
            float4 o4;
            o4.x = (t0 + tl0 + 0 < T_DIM) ? s[0] : 1e30f;   // padded t must never win the min
            o4.y = (t0 + tl0 + 1 < T_DIM) ? s[1] : 1e30f;
            o4.z = (t0 + tl0 + 2 < T_DIM) ? s[2] : 1e30f;
            o4.w = (t0 + tl0 + 3 < T_DIM) ? s[3] : 1e30f;
            *(float4*)(&x2p[w][tl0]) = o4;
        }
        __syncthreads();                           // barrier A: LDS tile ready

        if (it + 1 < itN) loadv(it + 1);           // issue next loads; overlap with MFMA

        f32x4 acc[4][2];
#pragma unroll
        for (int ps = 0; ps < 4; ++ps)
#pragma unroll
            for (int ts = 0; ts < 2; ++ts) acc[ps][ts] = (f32x4){0.f, 0.f, 0.f, 0.f};

#pragma unroll
        for (int kst = 0; kst < 4; ++kst) {
            short8 bfr[2];
#pragma unroll
            for (int ts = 0; ts < 2; ++ts) {
                const int tl = ts * 16 + row16;
                const int gr = (kst * 4 + kq) ^ (tl & 7);
                bfr[ts] = *(const short8*)(smem + tl * 256 + (gr << 4));
            }
#pragma unroll
            for (int ps = 0; ps < 4; ++ps)
#pragma unroll
                for (int ts = 0; ts < 2; ++ts)
                    acc[ps][ts] = __builtin_amdgcn_mfma_f32_16x16x32_bf16(
                        afr[ps][kst], bfr[ts], acc[ps][ts], 0, 0, 0);
        }

        const float x2v0 = x2p[0][row16]      + x2p[1][row16]      + x2p[2][row16]      + x2p[3][row16];
        const float x2v1 = x2p[0][16 + row16] + x2p[1][16 + row16] + x2p[2][16 + row16] + x2p[3][16 + row16];
#pragma unroll
        for (int ps = 0; ps < 4; ++ps)
#pragma unroll
            for (int q = 0; q < 4; ++q) {
                minv[ps][q] = fminf(minv[ps][q], fmaf(-2.f, acc[ps][0][q], x2v0));
                minv[ps][q] = fminf(minv[ps][q], fmaf(-2.f, acc[ps][1][q], x2v1));
            }
        __syncthreads();                           // barrier B: protect LDS for next writes
    }

    // min across the 16 t-columns (lane bits 0..3)
#pragma unroll
    for (int m = 1; m <= 8; m <<= 1)
#pragma unroll
        for (int ps = 0; ps < 4; ++ps)
#pragma unroll
            for (int q = 0; q < 4; ++q)
                minv[ps][q] = fminf(minv[ps][q], __shfl_xor(minv[ps][q], m));

    if (row16 == 0) {
#pragma unroll
        for (int ps = 0; ps < 4; ++ps)
#pragma unroll
            for (int q = 0; q < 4; ++q) {
                const int p = wp + ps * 16 + kq * 4 + q;   // C/D layout: row=(lane>>4)*4+reg
                if (p < P_DIM)
                    wsmin[((size_t)b * P_PAD + p) * 2 + th] = minv[ps][q];
            }
    }
}

// ---------------- combine: p2 + min-merge + clamp + log-sim + @W ----------------
__global__ __launch_bounds__(256) void combine_logits(
    const float* __restrict__ proto, const float* __restrict__ lw,
    const float* __restrict__ wsmin, float* __restrict__ out) {
    const int b = blockIdx.x, tid = threadIdx.x;
    float a[NCLS] = {0.f, 0.f, 0.f, 0.f, 0.f};
    for (int p = tid; p < P_DIM; p += 256) {
        const float4* pr = (const float4*)(proto + p * C_DIM);
        float p2 = 0.f;
#pragma unroll
        for (int i = 0; i < 32; ++i) {
            float4 u = pr[i];
            p2 += u.x*u.x + u.y*u.y + u.z*u.z + u.w*u.w;
        }
        const size_t base = ((size_t)b * P_PAD + p) * 2;
        const float m  = fminf(wsmin[base], wsmin[base + 1]);
        const float md = fmaxf(m + p2, 0.f);
        const float sim = logf((md + 1.f) / (md + EPSV));
#pragma unroll
        for (int n = 0; n < NCLS; ++n) a[n] = fmaf(sim, lw[p * NCLS + n], a[n]);
    }
#pragma unroll
    for (int m = 1; m <= 32; m <<= 1)
#pragma unroll
        for (int n = 0; n < NCLS; ++n) a[n] += __shfl_xor(a[n], m);
    __shared__ float red[4][NCLS];
    const int w = tid >> 6, l = tid & 63;
    if (l == 0) {
#pragma unroll
        for (int n = 0; n < NCLS; ++n) red[w][n] = a[n];
    }
    __syncthreads();
    if (tid < NCLS)
        out[b * NCLS + tid] = red[0][tid] + red[1][tid] + red[2][tid] + red[3][tid];
}

// ---------------- fallback (no workspace): slow but correct ----------------
__global__ __launch_bounds__(256) void fallback_k(const float* __restrict__ x,
                                                  const float* __restrict__ proto,
                                                  const float* __restrict__ lw,
                                                  float* __restrict__ out) {
    __shared__ float x2s[T_DIM];
    __shared__ float sims[P_DIM];
    int b = blockIdx.x, tid = threadIdx.x;
    for (int t = tid; t < T_DIM; t += 256) {
        float a = 0.f;
        for (int c = 0; c < C_DIM; ++c) { float v = x[((size_t)b * C_DIM + c) * T_DIM + t]; a = fmaf(v, v, a); }
        x2s[t] = a;
    }
    __syncthreads();
    for (int p = tid; p < P_DIM; p += 256) {
        float p2 = 0.f;
        for (int c = 0; c < C_DIM; ++c) { float v = proto[p * C_DIM + c]; p2 = fmaf(v, v, p2); }
        float mind = 1e30f;
        for (int t = 0; t < T_DIM; ++t) {
            float xp = 0.f;
            for (int c = 0; c < C_DIM; ++c)
                xp = fmaf(x[((size_t)b * C_DIM + c) * T_DIM + t], proto[p * C_DIM + c], xp);
            float d = fmaxf(x2s[t] - 2.f * xp + p2, 0.f);
            mind = fminf(mind, d);
        }
        sims[p] = logf((mind + 1.f) / (mind + EPSV));
    }
    __syncthreads();
    if (tid < NCLS) {
        float a = 0.f;
        for (int p = 0; p < P_DIM; ++p) a = fmaf(sims[p], lw[p * NCLS + tid], a);
        out[b * NCLS + tid] = a;
    }
}

extern "C" void kernel_launch(void* const* d_in, const int* in_sizes, int n_in,
                              void* d_out, int out_size, void* d_ws, size_t ws_size,
                              hipStream_t stream) {
    const float* x     = (const float*)d_in[0];
    const float* proto = (const float*)d_in[1];
    const float* lw    = (const float*)d_in[2];
    float* out = (float*)d_out;

    const size_t need = (size_t)B_DIM * P_PAD * 2 * sizeof(float);   // 512 KB

    if (ws_size >= need) {
        float* wsmin = (float*)d_ws;
        fused_gemm_min<<<dim3(512), 256, 0, stream>>>(x, proto, wsmin);
        combine_logits<<<dim3(B_DIM), 256, 0, stream>>>(proto, lw, wsmin, out);
    } else {
        fallback_k<<<dim3(B_DIM), 256, 0, stream>>>(x, proto, lw, out);
    }
}